// Round 5
// baseline (358.565 us; speedup 1.0000x reference)
//
#include <hip/hip_runtime.h>
#include <hip/hip_fp16.h>
#include <hip/hip_cooperative_groups.h>

namespace cg = cooperative_groups;

// MCLoss: mean |lap(gt) - lap(pr)| == mean |lap(gt - pr)|  (laplacian is linear).
// B=16, N=100000, M=9, nb[:,0]==i.
//
// ONE cooperative kernel:
//   phase A: tiled transpose+diff, d[i][b]=half4(gt-pr) in (N+1,16) layout
//            (row=128B=2 lines; round-4 proved 1-line rows collapse the gather
//            rate: throughput = lines_in_flight/latency, not bytes).
//   grid.sync()
//   phase B: round-2 winner gather (2 i x 1 b per thread, 18 loads up front),
//            block reduce -> atomicAdd.
//   grid.sync(); block 0 writes out.

#define NT 256
#define TI 64

union H4 { uint2 u; __half2 h[2]; };

__device__ __forceinline__ void unpackh(uint2 v, float& x, float& y, float& z) {
  H4 c; c.u = v;
  float2 xy = __half22float2(c.h[0]);
  x = xy.x; y = xy.y;
  z = __half2float(__low2half(c.h[1]));
}

__device__ __forceinline__ uint2 packh(float x, float y, float z) {
  H4 o; o.h[0] = __floats2half2_rn(x, y); o.h[1] = __floats2half2_rn(z, 0.0f);
  return o.u;
}

__global__ __launch_bounds__(NT, 4) void fused(
    const float* __restrict__ gt, const float* __restrict__ pr,
    const int* __restrict__ nb, const float* __restrict__ nn,
    uint2* __restrict__ dq, float* __restrict__ acc,
    float* __restrict__ out, float scale, int N) {
  __shared__ float sm[16][3 * TI + 4];
  const int t = threadIdx.x;
  const int nblk = gridDim.x;
  const int ntiles = (N + TI - 1) / TI;

  // ---------------- phase A: transpose + fp16 pack ----------------
  for (int tile = blockIdx.x; tile < ntiles; tile += nblk) {
    const int i0 = tile * TI;
    const int ni = min(TI, N - i0);
    const int nq = (3 * ni) >> 2;
    __syncthreads();                       // protect sm across iterations
#pragma unroll
    for (int k = 0; k < 3; k++) {          // 16 segs x 48 float4
      int flat = t + k * NT;
      int seg = flat / 48;
      int q = flat - seg * 48;
      if (q < nq) {
        const float4* ga = (const float4*)(gt + ((size_t)seg * N + i0) * 3);
        const float4* pa = (const float4*)(pr + ((size_t)seg * N + i0) * 3);
        float4 a = ga[q];
        float4 p = pa[q];
        *(float4*)&sm[seg][q * 4] =
            make_float4(a.x - p.x, a.y - p.y, a.z - p.z, a.w - p.w);
      }
    }
    __syncthreads();
#pragma unroll
    for (int k = 0; k < 4; k++) {          // coalesced 8B writes, (i,b) order
      int el = t + k * NT;
      int il = el >> 4, b = el & 15;
      if (il < ni)
        dq[(size_t)(i0 + il) * 16 + b] =
            packh(sm[b][il * 3], sm[b][il * 3 + 1], sm[b][il * 3 + 2]);
    }
  }
  if (blockIdx.x == 0) {
    if (t < 16) { uint2 z; z.x = 0u; z.y = 0u; dq[(size_t)N * 16 + t] = z; }
    if (t == 16) *acc = 0.0f;
  }

  cg::this_grid().sync();

  // ---------------- phase B: gather + reduce (r2 winner) ----------------
  float s = 0.0f;
  const int nchunk = ((N >> 1) * 16 + NT - 1) / NT;
  for (int chunk = blockIdx.x; chunk < nchunk; chunk += nblk) {
    const int f = chunk * NT + t;
    const int g = f >> 4;
    const int b = f & 15;
    const int i0 = g * 2, i1 = i0 + 1;
    if (i1 < N) {
      const int* rA = nb + (size_t)i0 * 9 + 1;
      int ia[8], ib[8];
#pragma unroll
      for (int j = 0; j < 8; j++) { ia[j] = rA[j]; ib[j] = rA[j + 9]; }
      float wA = nn[i0], wB = nn[i1];
      uint2 cA = dq[(size_t)i0 * 16 + b];
      uint2 cB = dq[(size_t)i1 * 16 + b];
      uint2 vA[8], vB[8];
#pragma unroll
      for (int j = 0; j < 8; j++) vA[j] = dq[(size_t)ia[j] * 16 + b];
#pragma unroll
      for (int j = 0; j < 8; j++) vB[j] = dq[(size_t)ib[j] * 16 + b];

      float ax, ay, az;
      unpackh(cA, ax, ay, az);
      ax *= wA; ay *= wA; az *= wA;
#pragma unroll
      for (int j = 0; j < 8; j++) {
        float x, y, z; unpackh(vA[j], x, y, z);
        ax -= x; ay -= y; az -= z;
      }
      s += fabsf(ax) + fabsf(ay) + fabsf(az);

      float bx, by, bz;
      unpackh(cB, bx, by, bz);
      bx *= wB; by *= wB; bz *= wB;
#pragma unroll
      for (int j = 0; j < 8; j++) {
        float x, y, z; unpackh(vB[j], x, y, z);
        bx -= x; by -= y; bz -= z;
      }
      s += fabsf(bx) + fabsf(by) + fabsf(bz);
    }
  }
#pragma unroll
  for (int off = 32; off > 0; off >>= 1) s += __shfl_down(s, off);
  __shared__ float part[NT / 64];
  if ((t & 63) == 0) part[t >> 6] = s;
  __syncthreads();
  if (t == 0) {
    float tt = part[0] + part[1] + part[2] + part[3];
    atomicAdd(acc, tt);
  }

  cg::this_grid().sync();
  if (blockIdx.x == 0 && t == 0) out[0] = atomicAdd(acc, 0.0f) * scale;
}

// ---------------- 2-launch fallback (r2 path, fused finalize) ----------------
__global__ __launch_bounds__(NT) void k1_diff_pack(
    const float* __restrict__ gt, const float* __restrict__ pr,
    uint2* __restrict__ dq, float* __restrict__ acc,
    unsigned* __restrict__ cnt, int N) {
  __shared__ float sm[16][3 * TI + 4];
  const int t = threadIdx.x;
  const int i0 = blockIdx.x * TI;
  const int ni = min(TI, N - i0);
  const int nq = (3 * ni) >> 2;
#pragma unroll
  for (int k = 0; k < 3; k++) {
    int flat = t + k * NT;
    int seg = flat / 48;
    int q = flat - seg * 48;
    if (q < nq) {
      const float4* ga = (const float4*)(gt + ((size_t)seg * N + i0) * 3);
      const float4* pa = (const float4*)(pr + ((size_t)seg * N + i0) * 3);
      float4 a = ga[q];
      float4 p = pa[q];
      *(float4*)&sm[seg][q * 4] =
          make_float4(a.x - p.x, a.y - p.y, a.z - p.z, a.w - p.w);
    }
  }
  __syncthreads();
#pragma unroll
  for (int k = 0; k < 4; k++) {
    int el = t + k * NT;
    int il = el >> 4, b = el & 15;
    if (il < ni)
      dq[(size_t)(i0 + il) * 16 + b] =
          packh(sm[b][il * 3], sm[b][il * 3 + 1], sm[b][il * 3 + 2]);
  }
  if (blockIdx.x == 0) {
    if (t < 16) { uint2 z; z.x = 0u; z.y = 0u; dq[(size_t)N * 16 + t] = z; }
    if (t == 16) *acc = 0.0f;
    if (t == 17) *cnt = 0u;
  }
}

__global__ __launch_bounds__(NT) void k2_lap_loss(
    const uint2* __restrict__ dq, const int* __restrict__ nb,
    const float* __restrict__ nn, float* __restrict__ acc,
    unsigned* __restrict__ cnt, float* __restrict__ out,
    float scale, int N, int nblocks) {
  const int f = blockIdx.x * NT + threadIdx.x;
  const int g = f >> 4, b = f & 15;
  const int i0 = g * 2, i1 = i0 + 1;
  float s = 0.0f;
  if (i1 < N) {
    const int* rA = nb + (size_t)i0 * 9 + 1;
    int ia[8], ib[8];
#pragma unroll
    for (int j = 0; j < 8; j++) { ia[j] = rA[j]; ib[j] = rA[j + 9]; }
    float wA = nn[i0], wB = nn[i1];
    uint2 cA = dq[(size_t)i0 * 16 + b];
    uint2 cB = dq[(size_t)i1 * 16 + b];
    uint2 vA[8], vB[8];
#pragma unroll
    for (int j = 0; j < 8; j++) vA[j] = dq[(size_t)ia[j] * 16 + b];
#pragma unroll
    for (int j = 0; j < 8; j++) vB[j] = dq[(size_t)ib[j] * 16 + b];
    float ax, ay, az;
    unpackh(cA, ax, ay, az);
    ax *= wA; ay *= wA; az *= wA;
#pragma unroll
    for (int j = 0; j < 8; j++) {
      float x, y, z; unpackh(vA[j], x, y, z);
      ax -= x; ay -= y; az -= z;
    }
    s = fabsf(ax) + fabsf(ay) + fabsf(az);
    float bx, by, bz;
    unpackh(cB, bx, by, bz);
    bx *= wB; by *= wB; bz *= wB;
#pragma unroll
    for (int j = 0; j < 8; j++) {
      float x, y, z; unpackh(vB[j], x, y, z);
      bx -= x; by -= y; bz -= z;
    }
    s += fabsf(bx) + fabsf(by) + fabsf(bz);
  }
#pragma unroll
  for (int off = 32; off > 0; off >>= 1) s += __shfl_down(s, off);
  __shared__ float part[NT / 64];
  if ((threadIdx.x & 63) == 0) part[threadIdx.x >> 6] = s;
  __syncthreads();
  if (threadIdx.x == 0) {
    float tt = part[0] + part[1] + part[2] + part[3];
    atomicAdd(acc, tt);
    __threadfence();
    unsigned done = atomicAdd(cnt, 1u);
    if (done == (unsigned)(nblocks - 1))
      out[0] = atomicAdd(acc, 0.0f) * scale;
  }
}

// ---------------- generic fallback (odd shapes) ----------------
__global__ void k0_zero(float* __restrict__ acc) {
  if (threadIdx.x == 0) *acc = 0.0f;
}

__global__ __launch_bounds__(NT) void k2_direct(
    const float* __restrict__ gt, const float* __restrict__ pr,
    const int* __restrict__ nb, const float* __restrict__ nn,
    float* __restrict__ acc, int N, int K, int B) {
  int u = blockIdx.x * NT + threadIdx.x;
  float s = 0.0f;
  if (u < B * N) {
    int b = u / N;
    int i = u - b * N;
    size_t cidx = ((size_t)b * N + i) * 3;
    float w = nn[i];
    float ax = (gt[cidx] - pr[cidx]) * w;
    float ay = (gt[cidx + 1] - pr[cidx + 1]) * w;
    float az = (gt[cidx + 2] - pr[cidx + 2]) * w;
    const int* row = nb + (size_t)i * (K + 1) + 1;
    for (int j = 0; j < K; j++) {
      int idx = row[j];
      if (idx < N) {
        size_t p = ((size_t)b * N + idx) * 3;
        ax -= (gt[p] - pr[p]);
        ay -= (gt[p + 1] - pr[p + 1]);
        az -= (gt[p + 2] - pr[p + 2]);
      }
    }
    s = fabsf(ax) + fabsf(ay) + fabsf(az);
  }
#pragma unroll
  for (int off = 32; off > 0; off >>= 1) s += __shfl_down(s, off);
  __shared__ float part[NT / 64];
  if ((threadIdx.x & 63) == 0) part[threadIdx.x >> 6] = s;
  __syncthreads();
  if (threadIdx.x == 0)
    atomicAdd(acc, part[0] + part[1] + part[2] + part[3]);
}

__global__ void k3_finalize(const float* __restrict__ acc,
                            float* __restrict__ out, float scale) {
  if (threadIdx.x == 0) out[0] = acc[0] * scale;
}

extern "C" void kernel_launch(void* const* d_in, const int* in_sizes, int n_in,
                              void* d_out, int out_size, void* d_ws, size_t ws_size,
                              hipStream_t stream) {
  const float* gt = (const float*)d_in[0];
  const float* pr = (const float*)d_in[1];
  const int*   nb = (const int*)d_in[2];
  const float* nn = (const float*)d_in[3];
  int N = in_sizes[3];           // 100000
  int M = in_sizes[2] / N;       // 9
  int K = M - 1;                 // 8

  float scale = 1.0f / (16.0f * (float)N * 3.0f);
  size_t dbytes = (size_t)(N + 1) * 16 * sizeof(uint2);
  size_t need = dbytes + 64;

  if (K == 8 && (N & 3) == 0 && in_sizes[0] == 16 * N * 3 && ws_size >= need) {
    uint2*    dq  = (uint2*)d_ws;
    float*    acc = (float*)((char*)d_ws + dbytes);
    unsigned* cnt = (unsigned*)(acc + 1);
    float*    outp = (float*)d_out;

    int maxb = 0;
    hipError_t oe = hipOccupancyMaxActiveBlocksPerMultiprocessor(
        &maxb, (const void*)fused, NT, 0);
    int grid = 0;
    if (oe == hipSuccess && maxb > 0) {
      grid = maxb * 256;             // 256 CUs
      if (grid > 2048) grid = 2048;  // >8/CU adds nothing
    }

    bool done = false;
    if (grid >= 256) {
      void* args[] = {(void*)&gt, (void*)&pr, (void*)&nb, (void*)&nn,
                      (void*)&dq, (void*)&acc, (void*)&outp,
                      (void*)&scale, (void*)&N};
      hipError_t e = hipLaunchCooperativeKernel(
          (const void*)fused, dim3(grid), dim3(NT), args, 0, stream);
      done = (e == hipSuccess);
    }
    if (!done) {
      int b1 = (N + TI - 1) / TI;
      k1_diff_pack<<<b1, NT, 0, stream>>>(gt, pr, dq, acc, cnt, N);
      int b2 = ((N >> 1) * 16 + NT - 1) / NT;
      k2_lap_loss<<<b2, NT, 0, stream>>>(dq, nb, nn, acc, cnt, outp,
                                         scale, N, b2);
    }
  } else {
    int B = in_sizes[0] / (N * 3);
    float* acc = (float*)d_ws;
    k0_zero<<<1, 64, 0, stream>>>(acc);
    int b2 = (B * N + NT - 1) / NT;
    k2_direct<<<b2, NT, 0, stream>>>(gt, pr, nb, nn, acc, N, K, B);
    k3_finalize<<<1, 64, 0, stream>>>(acc, (float*)d_out, scale);
  }
}

// Round 7
// 248.794 us; speedup vs baseline: 1.4412x; 1.4412x over previous
//
#include <hip/hip_runtime.h>
#include <hip/hip_fp16.h>

// MCLoss: mean |lap(gt) - lap(pr)| == mean |lap(gt - pr)|  (laplacian is linear).
// B=16, N=100000, M=9, nb[:,0]==i.
//
// Round-2 winner structure (empirical best: k2=45.6us), plus:
//  - fused finalize in k2 (completion counter; saves the k3 launch)
//  - NON-TEMPORAL gather loads (as u64 scalars — the builtin rejects HIP vector
//    types): 16 lanes consume each gathered 128B row in one instruction (zero
//    L1 reuse); bypassing L1 tests the L1-MSHR cap theory (r2 arithmetic: ~32
//    lines outstanding/CU == typical L1 miss-queue depth).
//
// Gather law (r2/r3/r4): throughput ∝ lines-per-load-instr at fixed waves;
// halving waves costs 1.5x. So: fp16 128B rows, 2-i/thread, 3125 blocks.

#define NT 256
#define TI 64

union H4 { unsigned long long u; __half2 h[2]; };

__device__ __forceinline__ void unpackh(unsigned long long v,
                                        float& x, float& y, float& z) {
  H4 c; c.u = v;
  float2 xy = __half22float2(c.h[0]);
  x = xy.x; y = xy.y;
  z = __half2float(__low2half(c.h[1]));
}

__device__ __forceinline__ unsigned long long packh(float x, float y, float z) {
  H4 o; o.h[0] = __floats2half2_rn(x, y); o.h[1] = __floats2half2_rn(z, 0.0f);
  return o.u;
}

__global__ __launch_bounds__(NT) void k1_diff_pack(
    const float* __restrict__ gt, const float* __restrict__ pr,
    unsigned long long* __restrict__ dq, float* __restrict__ acc,
    unsigned* __restrict__ cnt, int N) {
  __shared__ float sm[16][3 * TI + 4];
  const int t = threadIdx.x;
  const int i0 = blockIdx.x * TI;
  const int ni = min(TI, N - i0);        // N%4==0, TI%4==0
  const int nq = (3 * ni) >> 2;

  // Phase 1: 16 segments x 48 contiguous aligned float4 -> LDS
#pragma unroll
  for (int k = 0; k < 3; k++) {
    int flat = t + k * NT;
    int seg = flat / 48;
    int q = flat - seg * 48;
    if (q < nq) {
      const float4* ga = (const float4*)(gt + ((size_t)seg * N + i0) * 3);
      const float4* pa = (const float4*)(pr + ((size_t)seg * N + i0) * 3);
      float4 a = ga[q];
      float4 p = pa[q];
      *(float4*)&sm[seg][q * 4] =
          make_float4(a.x - p.x, a.y - p.y, a.z - p.z, a.w - p.w);
    }
  }
  __syncthreads();

  // Phase 2: coalesced 8B writes in transposed (i,b) order
#pragma unroll
  for (int k = 0; k < 4; k++) {
    int el = t + k * NT;
    int il = el >> 4, b = el & 15;
    if (il < ni)
      dq[(size_t)(i0 + il) * 16 + b] =
          packh(sm[b][il * 3], sm[b][il * 3 + 1], sm[b][il * 3 + 2]);
  }

  if (blockIdx.x == 0) {
    if (t < 16) dq[(size_t)N * 16 + t] = 0ull;
    if (t == 16) *acc = 0.0f;
    if (t == 17) *cnt = 0u;
  }
}

__global__ __launch_bounds__(NT) void k2_lap_loss(
    const unsigned long long* __restrict__ dq, const int* __restrict__ nb,
    const float* __restrict__ nn, float* __restrict__ acc,
    unsigned* __restrict__ cnt, float* __restrict__ out,
    float scale, int N, int nblocks) {
  const int f = blockIdx.x * NT + threadIdx.x;
  const int g = f >> 4;          // i-pair index
  const int b = f & 15;
  const int i0 = g * 2, i1 = i0 + 1;
  float s = 0.0f;

  if (i1 < N) {
    const int* rA = nb + (size_t)i0 * 9 + 1;
    int ia[8], ib[8];
#pragma unroll
    for (int j = 0; j < 8; j++) { ia[j] = rA[j]; ib[j] = rA[j + 9]; }
    float wA = nn[i0], wB = nn[i1];

    // 18 independent gathers in flight; non-temporal (bypass L1 — zero reuse)
    unsigned long long cA = __builtin_nontemporal_load(&dq[(size_t)i0 * 16 + b]);
    unsigned long long cB = __builtin_nontemporal_load(&dq[(size_t)i1 * 16 + b]);
    unsigned long long vA[8], vB[8];
#pragma unroll
    for (int j = 0; j < 8; j++)
      vA[j] = __builtin_nontemporal_load(&dq[(size_t)ia[j] * 16 + b]);
#pragma unroll
    for (int j = 0; j < 8; j++)
      vB[j] = __builtin_nontemporal_load(&dq[(size_t)ib[j] * 16 + b]);

    float ax, ay, az;
    unpackh(cA, ax, ay, az);
    ax *= wA; ay *= wA; az *= wA;
#pragma unroll
    for (int j = 0; j < 8; j++) {
      float x, y, z; unpackh(vA[j], x, y, z);
      ax -= x; ay -= y; az -= z;
    }
    s = fabsf(ax) + fabsf(ay) + fabsf(az);

    float bx, by, bz;
    unpackh(cB, bx, by, bz);
    bx *= wB; by *= wB; bz *= wB;
#pragma unroll
    for (int j = 0; j < 8; j++) {
      float x, y, z; unpackh(vB[j], x, y, z);
      bx -= x; by -= y; bz -= z;
    }
    s += fabsf(bx) + fabsf(by) + fabsf(bz);
  } else if (i0 < N) {
    float wA = nn[i0];
    float ax, ay, az;
    unpackh(dq[(size_t)i0 * 16 + b], ax, ay, az);
    ax *= wA; ay *= wA; az *= wA;
    for (int j = 1; j < 9; j++) {
      int idx = nb[(size_t)i0 * 9 + j];
      float x, y, z; unpackh(dq[(size_t)idx * 16 + b], x, y, z);
      ax -= x; ay -= y; az -= z;
    }
    s = fabsf(ax) + fabsf(ay) + fabsf(az);
  }

  // wave(64) -> block -> one atomic; last block finalizes
#pragma unroll
  for (int off = 32; off > 0; off >>= 1) s += __shfl_down(s, off);
  __shared__ float part[NT / 64];
  if ((threadIdx.x & 63) == 0) part[threadIdx.x >> 6] = s;
  __syncthreads();
  if (threadIdx.x == 0) {
    float tt = part[0] + part[1] + part[2] + part[3];
    atomicAdd(acc, tt);
    __threadfence();
    unsigned done = atomicAdd(cnt, 1u);
    if (done == (unsigned)(nblocks - 1))
      out[0] = atomicAdd(acc, 0.0f) * scale;
  }
}

// ---------------- generic fallback (odd shapes / tiny ws) ----------------
__global__ void k0_zero(float* __restrict__ acc) {
  if (threadIdx.x == 0) *acc = 0.0f;
}

__global__ __launch_bounds__(NT) void k2_direct(
    const float* __restrict__ gt, const float* __restrict__ pr,
    const int* __restrict__ nb, const float* __restrict__ nn,
    float* __restrict__ acc, int N, int K, int B) {
  int u = blockIdx.x * NT + threadIdx.x;
  float s = 0.0f;
  if (u < B * N) {
    int b = u / N;
    int i = u - b * N;
    size_t cidx = ((size_t)b * N + i) * 3;
    float w = nn[i];
    float ax = (gt[cidx] - pr[cidx]) * w;
    float ay = (gt[cidx + 1] - pr[cidx + 1]) * w;
    float az = (gt[cidx + 2] - pr[cidx + 2]) * w;
    const int* row = nb + (size_t)i * (K + 1) + 1;
    for (int j = 0; j < K; j++) {
      int idx = row[j];
      if (idx < N) {
        size_t p = ((size_t)b * N + idx) * 3;
        ax -= (gt[p] - pr[p]);
        ay -= (gt[p + 1] - pr[p + 1]);
        az -= (gt[p + 2] - pr[p + 2]);
      }
    }
    s = fabsf(ax) + fabsf(ay) + fabsf(az);
  }
#pragma unroll
  for (int off = 32; off > 0; off >>= 1) s += __shfl_down(s, off);
  __shared__ float part[NT / 64];
  if ((threadIdx.x & 63) == 0) part[threadIdx.x >> 6] = s;
  __syncthreads();
  if (threadIdx.x == 0)
    atomicAdd(acc, part[0] + part[1] + part[2] + part[3]);
}

__global__ void k3_finalize(const float* __restrict__ acc,
                            float* __restrict__ out, float scale) {
  if (threadIdx.x == 0) out[0] = acc[0] * scale;
}

extern "C" void kernel_launch(void* const* d_in, const int* in_sizes, int n_in,
                              void* d_out, int out_size, void* d_ws, size_t ws_size,
                              hipStream_t stream) {
  const float* gt = (const float*)d_in[0];
  const float* pr = (const float*)d_in[1];
  const int*   nb = (const int*)d_in[2];
  const float* nn = (const float*)d_in[3];
  int N = in_sizes[3];           // 100000
  int M = in_sizes[2] / N;       // 9
  int K = M - 1;                 // 8

  float scale = 1.0f / (16.0f * (float)N * 3.0f);
  size_t dbytes = (size_t)(N + 1) * 16 * sizeof(unsigned long long);
  size_t need = dbytes + 64;

  if (K == 8 && (N & 3) == 0 && in_sizes[0] == 16 * N * 3 && ws_size >= need) {
    unsigned long long* dq = (unsigned long long*)d_ws;
    float*    acc = (float*)((char*)d_ws + dbytes);
    unsigned* cnt = (unsigned*)(acc + 1);

    int b1 = (N + TI - 1) / TI;
    k1_diff_pack<<<b1, NT, 0, stream>>>(gt, pr, dq, acc, cnt, N);

    int b2 = ((N >> 1) * 16 + NT - 1) / NT;   // 3125 blocks
    k2_lap_loss<<<b2, NT, 0, stream>>>(dq, nb, nn, acc, cnt, (float*)d_out,
                                       scale, N, b2);
  } else {
    int B = in_sizes[0] / (N * 3);
    float* acc = (float*)d_ws;
    k0_zero<<<1, 64, 0, stream>>>(acc);
    int b2 = (B * N + NT - 1) / NT;
    k2_direct<<<b2, NT, 0, stream>>>(gt, pr, nb, nn, acc, N, K, B);
    k3_finalize<<<1, 64, 0, stream>>>(acc, (float*)d_out, scale);
  }
}